// Round 8
// baseline (102.864 us; speedup 1.0000x reference)
//
#include <hip/hip_runtime.h>
#include <limits.h>

#define HSIZE 2048          // d-histogram buckets (d capped at RMAX+1; 481 for this family)
#define CSH   6             // cell shift (64 px cells)
#define CSZ   64
#define MAXNC 4096          // max spatial cells (2160x3840/64 -> 2040 here)
#define MAXLP 10240         // max points staged in LDS (80 KB)
#define TPP   16            // threads per point in query
#define TPB   640           // query block size: 40 pts/block -> 250 blocks (<= 256 CUs, ONE round)

// ---------------- K1: build (single workgroup) ----------------
// zero hist+done; counting-sort points into cells (ppk/sidx); per-cell max score;
// meta = {RMAX, NCX, NCY}
__global__ __launch_bounds__(1024) void build_k(
    const int* __restrict__ kp, const float* __restrict__ sc,
    const int* __restrict__ nret_, const int* __restrict__ rows_, const int* __restrict__ cols_,
    int n, int* __restrict__ hist, int* __restrict__ meta, int* __restrict__ done,
    int* __restrict__ celloff, int* __restrict__ cellmax,
    int2* __restrict__ ppk, int* __restrict__ sidx) {
    __shared__ int cnt[MAXNC];
    __shared__ int cmx[MAXNC];
    __shared__ int wsum[16];
    int t = threadIdx.x, lane = t & 63, w = t >> 6;
    int rows = rows_[0], cols = cols_[0];
    int NCX = (cols + CSZ - 1) >> CSH;
    int NCY = (rows + CSZ - 1) >> CSH;
    int NC = NCX * NCY;                        // 2040 for this problem family (<= MAXNC)
    const int4* kp4 = (const int4*)kp;

    for (int i = t; i < MAXNC; i += 1024) { cnt[i] = 0; cmx[i] = 0; }
    for (int i = t; i < HSIZE; i += 1024) hist[i] = 0;
    if (t == 0) done[0] = 0;
    __syncthreads();
    for (int i = t; i < n; i += 1024) {
        int4 k = kp4[i];
        int c = (k.z >> CSH) * NCX + (k.w >> CSH);
        atomicAdd(&cnt[c], 1);
        atomicMax(&cmx[c], __float_as_int(sc[i]));   // scores > 0: bit order == value order
    }
    __syncthreads();
    // exclusive scan over MAXNC: 4 cells/thread, wave shfl scans (3 barriers total)
    int base = t * 4;
    int l0 = cnt[base], l1 = cnt[base + 1], l2 = cnt[base + 2], l3 = cnt[base + 3];
    int s = l0 + l1 + l2 + l3;
    int x = s;
    for (int o = 1; o < 64; o <<= 1) { int v = __shfl_up(x, o); if (lane >= o) x += v; }
    if (lane == 63) wsum[w] = x;
    __syncthreads();
    if (w == 0) {
        int v = (lane < 16) ? wsum[lane] : 0;
        for (int o = 1; o < 16; o <<= 1) { int u = __shfl_up(v, o); if (lane >= o) v += u; }
        if (lane < 16) wsum[lane] = v;               // inclusive wave totals
    }
    __syncthreads();
    int ex = ((w == 0) ? 0 : wsum[w - 1]) + x - s;   // exclusive prefix of this 4-cell group
    int o0 = ex, o1 = ex + l0, o2 = o1 + l1, o3 = o2 + l2;
    cnt[base] = o0; cnt[base + 1] = o1; cnt[base + 2] = o2; cnt[base + 3] = o3;   // scatter cursor
    if (base < NC)     celloff[base]     = o0;
    if (base + 1 < NC) celloff[base + 1] = o1;
    if (base + 2 < NC) celloff[base + 2] = o2;
    if (base + 3 < NC) celloff[base + 3] = o3;
    if (t == 0) celloff[NC] = n;
    __syncthreads();
    for (int i = t; i < n; i += 1024) {
        int4 k = kp4[i];
        int c = (k.z >> CSH) * NCX + (k.w >> CSH);
        int pos = atomicAdd(&cnt[c], 1);       // within-cell order nondeterministic; consumers commutative
        int2 v; v.x = (k.z << 16) | k.w; v.y = __float_as_int(sc[i]);
        ppk[pos] = v;
        sidx[pos] = i;
    }
    for (int i = t; i < NC; i += 1024) cellmax[i] = cmx[i];
    if (t == 0) {
        int nret = nret_[0];
        int mx = rows > cols ? rows : cols;
        int nr1 = nret > 1 ? nret : 1;
        int dvs = (int)sqrt((double)n / (double)nr1);   // Python int() truncation
        if (dvs < 1) dvs = 1;
        int high = mx / dvs; if (high < 1) high = 1;
        meta[0] = high / 2;                    // RMAX: no probed radius can exceed this
        meta[1] = NCX;
        meta[2] = NCY;
    }
}

// ---------------- K2: query (16 thr/pt, FULL LDS stage) + last-block finish ----------------
// LDS: lcell[MAXNC+1] int2 {off,max} 32.8 KB + lpp[MAXLP] int2 81.9 KB = 114.7 KB -> 1 block/CU.
// 250 blocks x 640 threads: single block-round over 256 CUs.
__global__ __launch_bounds__(TPB, 1) void query_finish_k(
    const int* __restrict__ kp, const float* __restrict__ sc,
    const int* __restrict__ nret_, const int* __restrict__ rows_, const int* __restrict__ cols_,
    const int* __restrict__ meta, int* __restrict__ done,
    const int* __restrict__ celloff, const int* __restrict__ cellmax,
    const int2* __restrict__ ppk, const int* __restrict__ sidx,
    int n, int* __restrict__ dd, int* __restrict__ hist,
    float* __restrict__ out) {
    __shared__ int2 lcell[MAXNC + 1];          // {celloff, cellmax}; reused as suf[] in finish
    __shared__ int2 lpp[MAXLP];                // packed points; reused as aux/wt in finish
    __shared__ int ticket_s;
    __shared__ int rsh;
    int t = threadIdx.x;
    int RMAX = meta[0], NCX = meta[1], NCY = meta[2];
    int NC = NCX * NCY;
    int gt = blockIdx.x * TPB + t;
    int q = gt >> 4, sub = gt & 15;
    bool act = q < n;

    // prefetch per-point globals BEFORE staging barrier (latency hides under staging)
    int2 me; me.x = 0; me.y = 0;
    int idx = 0, lo = 0, hi = 0, y = 0, x = 0, cy = 0, cx = 0;
    if (act) {
        me = ppk[q];
        idx = sidx[q];
        y = me.x >> 16; x = me.x & 0xFFFF;
        cy = y >> CSH;  cx = x >> CSH;
        int c0 = cy * NCX + cx;
        lo = celloff[c0]; hi = celloff[c0 + 1];
    }
    // stage cells (packed) + points into LDS
    for (int i = t; i <= NC; i += TPB) {
        int2 v; v.x = celloff[i]; v.y = (i < NC) ? cellmax[i] : 0;
        lcell[i] = v;
    }
    {
        int nh = n >> 1;
        const int4* src4 = (const int4*)ppk;
        int4* dst4 = (int4*)lpp;
        for (int i = t; i < nh; i += TPB) dst4[i] = src4[i];
        if ((n & 1) && t == 0) lpp[n - 1] = ppk[n - 1];
    }
    __syncthreads();

    if (act) {
        // same-pixel aggregates (duplicates share a cell): pixel-max score, min index
        int pb = me.y, mi = idx;
        for (int j = lo + sub; j < hi; j += TPP) {
            int2 v = lpp[j];
            if (v.x == me.x) {
                if (v.y > pb) pb = v.y;
                int ji = sidx[j]; if (ji < mi) mi = ji;
            }
        }
        pb = max(pb, __shfl_xor(pb, 1)); pb = max(pb, __shfl_xor(pb, 2));
        pb = max(pb, __shfl_xor(pb, 4)); pb = max(pb, __shfl_xor(pb, 8));
        mi = min(mi, __shfl_xor(mi, 1)); mi = min(mi, __shfl_xor(mi, 2));
        mi = min(mi, __shfl_xor(mi, 4)); mi = min(mi, __shfl_xor(mi, 8));

        // ring 0: own cell
        int d = RMAX + 1;                      // "no higher within RMAX" sentinel
        for (int j = lo + sub; j < hi; j += TPP) {
            int2 v = lpp[j];
            if (v.y > pb) {
                int dy = y - (v.x >> 16);   dy = dy < 0 ? -dy : dy;
                int dx = x - (v.x & 0xFFFF); dx = dx < 0 ? -dx : dx;
                int c = dy > dx ? dy : dx;
                if (c < d) d = c;
            }
        }
        d = min(d, __shfl_xor(d, 1)); d = min(d, __shfl_xor(d, 2));
        d = min(d, __shfl_xor(d, 4)); d = min(d, __shfl_xor(d, 8));

        // expanding rings; LB(R) = min possible distance from any ring-R cell
        for (int R = 1;; ++R) {
            int LB = (R - 1) * CSZ + 1;
            if (LB >= d) break;                // covers the d == RMAX+1 cap too
            for (int e = sub; e < 8 * R; e += TPP) {
                int a, b;
                if (e < 2 * R + 1)      { a = -R; b = -R + e; }
                else if (e < 4 * R + 2) { a =  R; b = -R + (e - (2 * R + 1)); }
                else { int ss = e - (4 * R + 2); a = -R + 1 + (ss >> 1); b = (ss & 1) ? R : -R; }
                int ccy = cy + a, ccx = cx + b;
                if (ccy < 0 || ccy >= NCY || ccx < 0 || ccx >= NCX) continue;
                int cc = ccy * NCX + ccx;
                int2 cm = lcell[cc];           // one ds_read_b64: {off, max}
                if (cm.y <= pb) continue;      // no strictly-greater score in this cell
                int jhi = lcell[cc + 1].x;
                for (int j = cm.x; j < jhi; ++j) {
                    int2 v = lpp[j];
                    if (v.y > pb) {
                        int dy = y - (v.x >> 16);   dy = dy < 0 ? -dy : dy;
                        int dx = x - (v.x & 0xFFFF); dx = dx < 0 ? -dx : dx;
                        int c = dy > dx ? dy : dx;
                        if (c < d) d = c;
                    }
                }
            }
            d = min(d, __shfl_xor(d, 1)); d = min(d, __shfl_xor(d, 2));
            d = min(d, __shfl_xor(d, 4)); d = min(d, __shfl_xor(d, 8));
        }
        if (sub == 0) {
            dd[idx] = d;                                   // single writer per point
            if (mi == idx) atomicAdd(&hist[d < HSIZE ? d : HSIZE - 1], 1);
        }
    }

    // ---- completion election: last finished block runs the finish phase ----
    __threadfence();                                       // release dd/hist to device scope
    if (t == 0) ticket_s = atomicAdd(done, 1);
    __syncthreads();
    if (ticket_s != (int)gridDim.x - 1) return;
    __threadfence();                                       // acquire others' writes

    // ---- finish phase (one block, TPB threads); reuse LDS ----
    int* suf = (int*)lcell;       // [HSIZE+1] <= 2*(MAXNC+1)
    int* aux = (int*)lpp;         // [1024]
    int* wtK = ((int*)lpp) + 1100;// [10]
    int* wtN = ((int*)lpp) + 1150;// [10]
    int nret = nret_[0];

    // suffix sums of hist (512 threads x 4 buckets): suf[v] = # pixels with d >= v
    int s0 = 0, s1 = 0, s2 = 0, s3 = 0;
    if (t < 512) {
        int base = t * 4;
        int b0 = hist[base], b1 = hist[base + 1], b2 = hist[base + 2], b3 = hist[base + 3];
        s3 = b3; s2 = b2 + s3; s1 = b1 + s2; s0 = b0 + s1;
        aux[t] = s0;
    }
    __syncthreads();
    for (int st = 1; st < 512; st <<= 1) {
        int v = (t < 512 && t + st < 512) ? aux[t + st] : 0;
        __syncthreads();
        if (t < 512) aux[t] += v;
        __syncthreads();
    }
    if (t < 512) {
        int base = t * 4;
        int after = (t < 511) ? aux[t + 1] : 0;
        suf[base] = s0 + after; suf[base + 1] = s1 + after;
        suf[base + 2] = s2 + after; suf[base + 3] = s3 + after;
    }
    if (t == 0) suf[HSIZE] = 0;
    __syncthreads();

    if (t == 0) {
        int rows = rows_[0], cols = cols_[0];
        int kmin = (int)llround((double)nret * (1.0 - 0.1));
        int kmax = (int)llround((double)nret * (1.0 + 0.1));
        int mx = rows > cols ? rows : cols;
        int nr1 = nret > 1 ? nret : 1;
        int dvs = (int)sqrt((double)n / (double)nr1);
        if (dvs < 1) dvs = 1;
        int high = mx / dvs; if (high < 1) high = 1;
        int low = 1, prev_k = -1, r_final = -1;
        bool found = false;
        while (true) {
            int k = (low + high) / 2;
            if (k == prev_k || low > high) break;
            int r = k / 2;                               // == k_odd // 2 for both parities
            int cnt = (r + 1 <= HSIZE) ? suf[r + 1] : 0;
            if (cnt >= kmin && cnt <= kmax) { r_final = r; found = true; break; }
            else if (cnt < kmin) high = k - 1;
            else low = k + 1;
            prev_k = k;
        }
        if (!found) {
            int kfb = prev_k > 0 ? prev_k : 1;
            r_final = kfb / 2;
        }
        rsh = r_final;
    }
    __syncthreads();
    int r = rsh;

    // total kept points m (pad aux to 1024, po2 tree)
    int c = 0;
    for (int i = t; i < n; i += TPB) c += (dd[i] > r) ? 1 : 0;
    aux[t] = c;
    for (int i = t + TPB; i < 1024; i += TPB) aux[i] = 0;
    __syncthreads();
    for (int st = 512; st > 0; st >>= 1) {
        if (t < st) aux[t] += aux[t + st];
        __syncthreads();
    }
    int m = aux[0];
    __syncthreads();

    // ordered selection: kept ascending, pad with non-kept ascending, truncate at nret
    int lane = t & 63;
    int w10 = t >> 6;
    unsigned long long lanemask = (lane == 0) ? 0ull : (~0ull >> (64 - lane));
    int runK = 0, runN = 0;
    for (int bb = 0; bb < n; bb += TPB) {
        int i = bb + t;
        bool valid = i < n;
        bool f  = valid && (dd[i] > r);
        bool nf = valid && !f;
        unsigned long long mk = __ballot(f);
        unsigned long long mn = __ballot(nf);
        int pk = __popcll(mk & lanemask);
        int pn = __popcll(mn & lanemask);
        if (lane == 0) { wtK[w10] = __popcll(mk); wtN[w10] = __popcll(mn); }
        __syncthreads();
        int exK = runK + pk, exN = runN + pn;
        for (int u = 0; u < w10; ++u) { exK += wtK[u]; exN += wtN[u]; }
        int ctK = 0, ctN = 0;
        for (int u = 0; u < 10; ++u) { ctK += wtK[u]; ctN += wtN[u]; }
        __syncthreads();
        if (valid) {
            int slot = -1;
            if (f) {
                if (exK < nret) slot = exK;
            } else if (nf && m < nret && (m + exN) < nret) {
                slot = m + exN;
            }
            if (slot >= 0) {
                out[slot * 4 + 0] = (float)kp[i * 4 + 0];
                out[slot * 4 + 1] = (float)kp[i * 4 + 1];
                out[slot * 4 + 2] = (float)kp[i * 4 + 2];
                out[slot * 4 + 3] = (float)kp[i * 4 + 3];
                out[nret * 4 + slot] = sc[i];
            }
        }
        runK += ctK;
        runN += ctN;
    }
}

extern "C" void kernel_launch(void* const* d_in, const int* in_sizes, int n_in,
                              void* d_out, int out_size, void* d_ws, size_t ws_size,
                              hipStream_t stream) {
    const int*   kp   = (const int*)d_in[0];
    const float* sc   = (const float*)d_in[1];
    const int*   nret = (const int*)d_in[2];
    const int*   rows = (const int*)d_in[3];
    const int*   cols = (const int*)d_in[4];
    int n = in_sizes[1];                       // number of points

    int* hist    = (int*)d_ws;                 // HSIZE
    int* meta    = hist + HSIZE;               // 8
    int* done    = meta + 8;                   // 8
    int* celloff = done + 8;                   // MAXNC+16
    int* cellmax = celloff + MAXNC + 16;       // MAXNC
    int2* ppk    = (int2*)(cellmax + MAXNC);   // n int2 (8B-aligned: offset even)
    int* sidx    = (int*)(ppk + n);            // n
    int* dd      = sidx + n;                   // n
    float* out   = (float*)d_out;

    build_k<<<1, 1024, 0, stream>>>(kp, sc, nret, rows, cols, n,
                                    hist, meta, done, celloff, cellmax, ppk, sidx);
    int qblocks = (TPP * n + TPB - 1) / TPB;   // 250 for n=10000
    query_finish_k<<<qblocks, TPB, 0, stream>>>(kp, sc, nret, rows, cols,
                                                meta, done, celloff, cellmax,
                                                ppk, sidx, n, dd, hist, out);
}

// Round 9
// 77.940 us; speedup vs baseline: 1.3198x; 1.3198x over previous
//
#include <hip/hip_runtime.h>
#include <limits.h>

#define HSIZE 2048          // d-histogram buckets (d capped at RMAX+1; 481 for this family)
#define CSH   6             // cell shift (64 px cells)
#define CSZ   64
#define MAXNC 4096          // max spatial cells (2160x3840/64 -> 2040 here)
#define MAXLP 10240         // max points staged in LDS (80 KB)
#define TPP   16            // threads per point in query
#define TPB   640           // 40 pts/block -> 250 blocks for n=10000: ONE round over 256 CUs

// ---------------- accessors so the ring walk compiles for LDS and global paths ----------------
struct LdsAcc {
    const int2* cell; const int2* pt;
    __device__ __forceinline__ int2 cellAt(int i) const { return cell[i]; }
    __device__ __forceinline__ int2 ptAt(int i)   const { return pt[i]; }
};
struct GblAcc {
    const int* off; const int* mx; const int2* pt; int NC;
    __device__ __forceinline__ int2 cellAt(int i) const {
        int2 v; v.x = off[i]; v.y = (i < NC) ? mx[i] : 0; return v;
    }
    __device__ __forceinline__ int2 ptAt(int i)   const { return pt[i]; }
};

// d = min Chebyshev distance to any strictly-higher-scored point, capped at RMAX+1.
// TPP threads cooperate per point (sub = lane role); shfl combines stay in 16-lane groups.
template<class Acc>
__device__ __forceinline__ int ringwalk(const Acc& A, int NCX, int NCY, int RMAX,
                                        int sub, int y, int x, int cy, int cx,
                                        int pb, int lo, int hi) {
    int d = RMAX + 1;                          // "no higher within RMAX" sentinel
    for (int j = lo + sub; j < hi; j += TPP) { // ring 0: own cell
        int2 v = A.ptAt(j);
        if (v.y > pb) {
            int dy = y - (v.x >> 16);    dy = dy < 0 ? -dy : dy;
            int dx = x - (v.x & 0xFFFF); dx = dx < 0 ? -dx : dx;
            int c = dy > dx ? dy : dx;
            if (c < d) d = c;
        }
    }
    d = min(d, __shfl_xor(d, 1)); d = min(d, __shfl_xor(d, 2));
    d = min(d, __shfl_xor(d, 4)); d = min(d, __shfl_xor(d, 8));

    for (int R = 1;; ++R) {                    // expanding rings
        int LB = (R - 1) * CSZ + 1;            // min possible distance from any ring-R cell
        if (LB >= d) break;                    // covers the d == RMAX+1 cap too
        for (int e = sub; e < 8 * R; e += TPP) {
            int a, b;
            if (e < 2 * R + 1)      { a = -R; b = -R + e; }
            else if (e < 4 * R + 2) { a =  R; b = -R + (e - (2 * R + 1)); }
            else { int ss = e - (4 * R + 2); a = -R + 1 + (ss >> 1); b = (ss & 1) ? R : -R; }
            int ccy = cy + a, ccx = cx + b;
            if (ccy < 0 || ccy >= NCY || ccx < 0 || ccx >= NCX) continue;
            int cc = ccy * NCX + ccx;
            int2 cm = A.cellAt(cc);            // one ds_read_b64: {off, max}
            if (cm.y <= pb) continue;          // no strictly-greater score in this cell
            int jhi = A.cellAt(cc + 1).x;
            for (int j = cm.x; j < jhi; ++j) {
                int2 v = A.ptAt(j);
                if (v.y > pb) {
                    int dy = y - (v.x >> 16);    dy = dy < 0 ? -dy : dy;
                    int dx = x - (v.x & 0xFFFF); dx = dx < 0 ? -dx : dx;
                    int c = dy > dx ? dy : dx;
                    if (c < d) d = c;
                }
            }
        }
        d = min(d, __shfl_xor(d, 1)); d = min(d, __shfl_xor(d, 2));
        d = min(d, __shfl_xor(d, 4)); d = min(d, __shfl_xor(d, 8));
    }
    return d;
}

// ---------------- K1: build (single workgroup) ----------------
// zero hist; counting-sort points into cells (ppk/sidx); per-cell max score; meta={RMAX,NCX,NCY}
__global__ __launch_bounds__(1024) void build_k(
    const int* __restrict__ kp, const float* __restrict__ sc,
    const int* __restrict__ nret_, const int* __restrict__ rows_, const int* __restrict__ cols_,
    int n, int* __restrict__ hist, int* __restrict__ meta,
    int* __restrict__ celloff, int* __restrict__ cellmax,
    int2* __restrict__ ppk, int* __restrict__ sidx) {
    __shared__ int cnt[MAXNC];
    __shared__ int cmx[MAXNC];
    __shared__ int wsum[16];
    int t = threadIdx.x, lane = t & 63, w = t >> 6;
    int rows = rows_[0], cols = cols_[0];
    int NCX = (cols + CSZ - 1) >> CSH;
    int NCY = (rows + CSZ - 1) >> CSH;
    int NC = NCX * NCY;                        // 2040 for this problem family (<= MAXNC)
    const int4* kp4 = (const int4*)kp;

    for (int i = t; i < MAXNC; i += 1024) { cnt[i] = 0; cmx[i] = 0; }
    for (int i = t; i < HSIZE; i += 1024) hist[i] = 0;
    __syncthreads();
    for (int i = t; i < n; i += 1024) {
        int4 k = kp4[i];
        int c = (k.z >> CSH) * NCX + (k.w >> CSH);
        atomicAdd(&cnt[c], 1);
        atomicMax(&cmx[c], __float_as_int(sc[i]));   // scores > 0: bit order == value order
    }
    __syncthreads();
    // exclusive scan over MAXNC: 4 cells/thread, wave shfl scans (3 barriers total)
    int base = t * 4;
    int l0 = cnt[base], l1 = cnt[base + 1], l2 = cnt[base + 2], l3 = cnt[base + 3];
    int s = l0 + l1 + l2 + l3;
    int x = s;
    for (int o = 1; o < 64; o <<= 1) { int v = __shfl_up(x, o); if (lane >= o) x += v; }
    if (lane == 63) wsum[w] = x;
    __syncthreads();
    if (w == 0) {
        int v = (lane < 16) ? wsum[lane] : 0;
        for (int o = 1; o < 16; o <<= 1) { int u = __shfl_up(v, o); if (lane >= o) v += u; }
        if (lane < 16) wsum[lane] = v;               // inclusive wave totals
    }
    __syncthreads();
    int ex = ((w == 0) ? 0 : wsum[w - 1]) + x - s;   // exclusive prefix of this 4-cell group
    int o0 = ex, o1 = ex + l0, o2 = o1 + l1, o3 = o2 + l2;
    cnt[base] = o0; cnt[base + 1] = o1; cnt[base + 2] = o2; cnt[base + 3] = o3;   // scatter cursor
    if (base < NC)     celloff[base]     = o0;
    if (base + 1 < NC) celloff[base + 1] = o1;
    if (base + 2 < NC) celloff[base + 2] = o2;
    if (base + 3 < NC) celloff[base + 3] = o3;
    if (t == 0) celloff[NC] = n;
    __syncthreads();
    for (int i = t; i < n; i += 1024) {
        int4 k = kp4[i];
        int c = (k.z >> CSH) * NCX + (k.w >> CSH);
        int pos = atomicAdd(&cnt[c], 1);       // within-cell order nondeterministic; consumers commutative
        int2 v; v.x = (k.z << 16) | k.w; v.y = __float_as_int(sc[i]);
        ppk[pos] = v;
        sidx[pos] = i;
    }
    for (int i = t; i < NC; i += 1024) cellmax[i] = cmx[i];
    if (t == 0) {
        int nret = nret_[0];
        int mx = rows > cols ? rows : cols;
        int nr1 = nret > 1 ? nret : 1;
        int dvs = (int)sqrt((double)n / (double)nr1);   // Python int() truncation
        if (dvs < 1) dvs = 1;
        int high = mx / dvs; if (high < 1) high = 1;
        meta[0] = high / 2;                    // RMAX: no probed radius can exceed this
        meta[1] = NCX;
        meta[2] = NCY;
    }
}

// ---------------- K2: query (16 thr/pt, full LDS stage, one block-round) ----------------
// LDS: lcell[MAXNC+1] int2 32.8 KB + lpp[MAXLP] int2 81.9 KB = 114.7 KB -> 1 block/CU.
__global__ __launch_bounds__(TPB, 1) void query_k(
    const int* __restrict__ meta,
    const int* __restrict__ celloff, const int* __restrict__ cellmax,
    const int2* __restrict__ ppk, const int* __restrict__ sidx,
    int n, int* __restrict__ dd, int* __restrict__ hist) {
    __shared__ int2 lcell[MAXNC + 1];          // {celloff, cellmax}
    __shared__ int2 lpp[MAXLP];                // packed points {(y<<16)|x, score_bits}
    int t = threadIdx.x;
    int RMAX = meta[0], NCX = meta[1], NCY = meta[2];
    int NC = NCX * NCY;
    int gt = blockIdx.x * TPB + t;
    int q = gt >> 4, sub = gt & 15;
    bool act = q < n;

    // prefetch per-point globals BEFORE staging barrier (latency hides under staging)
    int2 me; me.x = 0; me.y = 0;
    int idx = 0, lo = 0, hi = 0, y = 0, x = 0, cy = 0, cx = 0;
    if (act) {
        me = ppk[q];
        idx = sidx[q];
        y = me.x >> 16; x = me.x & 0xFFFF;
        cy = y >> CSH;  cx = x >> CSH;
        int c0 = cy * NCX + cx;
        lo = celloff[c0]; hi = celloff[c0 + 1];
    }
    bool cellsL = (NC <= MAXNC);
    bool ptsL   = (n <= MAXLP);
    if (cellsL) {
        for (int i = t; i <= NC; i += TPB) {
            int2 v; v.x = celloff[i]; v.y = (i < NC) ? cellmax[i] : 0;
            lcell[i] = v;
        }
    }
    if (ptsL) {
        int nh = n >> 1;
        const int4* src4 = (const int4*)ppk;
        int4* dst4 = (int4*)lpp;
        for (int i = t; i < nh; i += TPB) dst4[i] = src4[i];
        if ((n & 1) && t == 0) lpp[n - 1] = ppk[n - 1];
    }
    __syncthreads();

    if (act) {
        const int2* P = ptsL ? (const int2*)lpp : ppk;
        // same-pixel aggregates (duplicates share a cell): pixel-max score, min index
        int pb = me.y, mi = idx;
        for (int j = lo + sub; j < hi; j += TPP) {
            int2 v = P[j];
            if (v.x == me.x) {
                if (v.y > pb) pb = v.y;
                int ji = sidx[j]; if (ji < mi) mi = ji;
            }
        }
        pb = max(pb, __shfl_xor(pb, 1)); pb = max(pb, __shfl_xor(pb, 2));
        pb = max(pb, __shfl_xor(pb, 4)); pb = max(pb, __shfl_xor(pb, 8));
        mi = min(mi, __shfl_xor(mi, 1)); mi = min(mi, __shfl_xor(mi, 2));
        mi = min(mi, __shfl_xor(mi, 4)); mi = min(mi, __shfl_xor(mi, 8));

        int d;
        if (cellsL && ptsL) {
            LdsAcc A; A.cell = lcell; A.pt = lpp;
            d = ringwalk(A, NCX, NCY, RMAX, sub, y, x, cy, cx, pb, lo, hi);
        } else {
            GblAcc A; A.off = celloff; A.mx = cellmax; A.pt = ppk; A.NC = NC;
            d = ringwalk(A, NCX, NCY, RMAX, sub, y, x, cy, cx, pb, lo, hi);
        }
        if (sub == 0) {
            dd[idx] = d;                                   // single writer per point
            if (mi == idx) atomicAdd(&hist[d < HSIZE ? d : HSIZE - 1], 1);
        }
    }
}

// ---------------- K3: binary-search replica + ordered select (one block) ----------------
__global__ __launch_bounds__(1024) void finish_k(
    const int* __restrict__ kp, const float* __restrict__ sc,
    const int* __restrict__ dd, const int* __restrict__ hist,
    const int* __restrict__ nret_, const int* __restrict__ rows_, const int* __restrict__ cols_,
    int n, float* __restrict__ out) {
    __shared__ int suf[HSIZE + 1];
    __shared__ int aux[1024];
    __shared__ int wtK[16], wtN[16];
    __shared__ int rsh;
    int t = threadIdx.x;

    // suffix sums of hist: suf[v] = # pixels with d >= v
    int base = t * 2;
    int b0 = hist[base], b1 = hist[base + 1];
    int s1 = b1, s0 = b0 + b1;
    aux[t] = s0;
    __syncthreads();
    for (int st = 1; st < 1024; st <<= 1) {
        int v = (t + st < 1024) ? aux[t + st] : 0;
        __syncthreads();
        aux[t] += v;
        __syncthreads();
    }
    int after = (t < 1023) ? aux[t + 1] : 0;
    suf[base] = s0 + after; suf[base + 1] = s1 + after;
    if (t == 0) suf[HSIZE] = 0;
    __syncthreads();

    if (t == 0) {
        int nret = nret_[0];
        int rows = rows_[0], cols = cols_[0];
        int kmin = (int)llround((double)nret * (1.0 - 0.1));
        int kmax = (int)llround((double)nret * (1.0 + 0.1));
        int mx = rows > cols ? rows : cols;
        int nr1 = nret > 1 ? nret : 1;
        int dvs = (int)sqrt((double)n / (double)nr1);
        if (dvs < 1) dvs = 1;
        int high = mx / dvs; if (high < 1) high = 1;
        int low = 1, prev_k = -1, r_final = -1;
        bool found = false;
        while (true) {
            int k = (low + high) / 2;
            if (k == prev_k || low > high) break;
            int r = k / 2;                               // == k_odd // 2 for both parities
            int cnt = (r + 1 <= HSIZE) ? suf[r + 1] : 0;
            if (cnt >= kmin && cnt <= kmax) { r_final = r; found = true; break; }
            else if (cnt < kmin) high = k - 1;
            else low = k + 1;
            prev_k = k;
        }
        if (!found) {
            int kfb = prev_k > 0 ? prev_k : 1;
            r_final = kfb / 2;
        }
        rsh = r_final;
    }
    __syncthreads();
    int r = rsh;
    int nret = nret_[0];

    // total kept points m
    int c = 0;
    for (int i = t; i < n; i += 1024) c += (dd[i] > r) ? 1 : 0;
    aux[t] = c;
    __syncthreads();
    for (int st = 512; st > 0; st >>= 1) {
        if (t < st) aux[t] += aux[t + st];
        __syncthreads();
    }
    int m = aux[0];
    __syncthreads();

    // ordered selection: kept ascending, pad with non-kept ascending, truncate at nret
    int lane = t & 63;
    int w = t >> 6;
    unsigned long long lanemask = (lane == 0) ? 0ull : (~0ull >> (64 - lane));
    int runK = 0, runN = 0;
    for (int bb = 0; bb < n; bb += 1024) {
        int i = bb + t;
        bool valid = i < n;
        bool f  = valid && (dd[i] > r);
        bool nf = valid && !f;
        unsigned long long mk = __ballot(f);
        unsigned long long mn = __ballot(nf);
        int pk = __popcll(mk & lanemask);
        int pn = __popcll(mn & lanemask);
        if (lane == 0) { wtK[w] = __popcll(mk); wtN[w] = __popcll(mn); }
        __syncthreads();
        int exK = runK + pk, exN = runN + pn;
        for (int u = 0; u < w; ++u) { exK += wtK[u]; exN += wtN[u]; }
        int ctK = 0, ctN = 0;
        for (int u = 0; u < 16; ++u) { ctK += wtK[u]; ctN += wtN[u]; }
        __syncthreads();
        if (valid) {
            int slot = -1;
            if (f) {
                if (exK < nret) slot = exK;
            } else if (nf && m < nret && (m + exN) < nret) {
                slot = m + exN;
            }
            if (slot >= 0) {
                out[slot * 4 + 0] = (float)kp[i * 4 + 0];
                out[slot * 4 + 1] = (float)kp[i * 4 + 1];
                out[slot * 4 + 2] = (float)kp[i * 4 + 2];
                out[slot * 4 + 3] = (float)kp[i * 4 + 3];
                out[nret * 4 + slot] = sc[i];
            }
        }
        runK += ctK;
        runN += ctN;
    }
}

extern "C" void kernel_launch(void* const* d_in, const int* in_sizes, int n_in,
                              void* d_out, int out_size, void* d_ws, size_t ws_size,
                              hipStream_t stream) {
    const int*   kp   = (const int*)d_in[0];
    const float* sc   = (const float*)d_in[1];
    const int*   nret = (const int*)d_in[2];
    const int*   rows = (const int*)d_in[3];
    const int*   cols = (const int*)d_in[4];
    int n = in_sizes[1];                       // number of points

    int* hist    = (int*)d_ws;                 // HSIZE
    int* meta    = hist + HSIZE;               // 16
    int* celloff = meta + 16;                  // MAXNC+16
    int* cellmax = celloff + MAXNC + 16;       // MAXNC
    int2* ppk    = (int2*)(cellmax + MAXNC);   // n int2 (8B-aligned: offset even)
    int* sidx    = (int*)(ppk + n);            // n
    int* dd      = sidx + n;                   // n
    float* out   = (float*)d_out;

    build_k<<<1, 1024, 0, stream>>>(kp, sc, nret, rows, cols, n,
                                    hist, meta, celloff, cellmax, ppk, sidx);
    int qblocks = (TPP * n + TPB - 1) / TPB;   // 250 for n=10000
    query_k<<<qblocks, TPB, 0, stream>>>(meta, celloff, cellmax, ppk, sidx, n, dd, hist);
    finish_k<<<1, 1024, 0, stream>>>(kp, sc, dd, hist, nret, rows, cols, n, out);
}